// Round 7
// baseline (249.269 us; speedup 1.0000x reference)
//
#include <hip/hip_runtime.h>
#include <math.h>

// DeepWalk forward: embedding gathers + per-pair dot products -> loss & MRR.
// Round 7: round-4 structure (best measured: fused, 16 lanes/pair,
// grid-stride 2048 blocks) plus two cache/occupancy micro-levers:
//   - NT loads for pair-phase src rows + index arrays (mostly single-use)
//     to keep L2/LLC capacity for the ctx-row repeats (~237MB of re-reads).
//   - __launch_bounds__(256, 8) to force <=64 VGPR -> 32 waves/CU and a
//     single clean dispatch round for 2048 blocks.
// If this doesn't move (>=~124us), we are at the random-gather HBM wall
// (mandatory ~550MB unique + ~100-150MB L3-miss re-fetch @ ~5-5.5 TB/s).

constexpr int DIM  = 128;
constexpr int NNEG = 8;

typedef float f32x4 __attribute__((ext_vector_type(4)));
typedef int   i32x4 __attribute__((ext_vector_type(4)));

__global__ __launch_bounds__(256, 8) void fused(
    const int*   __restrict__ inputs,
    const int*   __restrict__ src,
    const int*   __restrict__ pos,
    const int*   __restrict__ negs,
    const float* __restrict__ tgt,
    const float* __restrict__ ctx,
    float*       __restrict__ out_emb,
    float*       __restrict__ out_ctx,
    float*       __restrict__ partials,   // [gridDim.x * 2]
    int b_in,
    int n_pairs)
{
    const int tid     = blockIdx.x * blockDim.x + threadIdx.x;
    const int nthread = gridDim.x * blockDim.x;

    // ---------------- phase 1: output gathers (copy, no reuse) -------------
    // one wave handles one input row for BOTH tables (lanes 0-31 tgt,
    // lanes 32-63 ctx); index load is wave-uniform; non-temporal to keep
    // L2/LLC for the pair phase's table rows.
    {
        const int total = b_in * 64;
        for (int u = tid; u < total; u += nthread) {
            int row   = u >> 6;
            int sub   = u & 63;
            int table = sub >> 5;
            int lane  = sub & 31;
            size_t idx = (size_t)inputs[row];
            const f32x4* s = (const f32x4*)((table ? ctx : tgt) + idx * DIM);
            f32x4 v = __builtin_nontemporal_load(s + lane);
            f32x4* d = (f32x4*)((table ? out_ctx : out_emb) + (size_t)row * DIM);
            __builtin_nontemporal_store(v, d + lane);
        }
    }

    // ---------------- phase 2: pair loss / mrr -----------------------------
    // 16 lanes per pair (lane holds 8 floats = 2 x float4), 4 pairs per wave,
    // grid-stride (4 iterations at 2048 blocks).
    const int lane = threadIdx.x & 63;
    const int l16  = threadIdx.x & 15;
    const int gid  = tid >> 4;
    const int ngroups = nthread >> 4;

    float loss_acc = 0.0f;
    float mrr_acc  = 0.0f;

    for (int b = gid; b < n_pairs; b += ngroups) {
        // src row: single-use (~88% unique) -> non-temporal, keep LLC for ctx
        int sidx = __builtin_nontemporal_load(src + b);      // group-uniform
        const f32x4* srow = (const f32x4*)(tgt + (size_t)sidx * DIM);
        f32x4 e0 = __builtin_nontemporal_load(srow + l16 * 2 + 0);
        f32x4 e1 = __builtin_nontemporal_load(srow + l16 * 2 + 1);

        int ci[1 + NNEG];
        ci[0] = __builtin_nontemporal_load(pos + b);
        const i32x4* np = (const i32x4*)(negs + (size_t)b * NNEG);
        i32x4 n0 = __builtin_nontemporal_load(np + 0);
        i32x4 n1 = __builtin_nontemporal_load(np + 1);
        ci[1] = n0.x; ci[2] = n0.y; ci[3] = n0.z; ci[4] = n0.w;
        ci[5] = n1.x; ci[6] = n1.y; ci[7] = n1.z; ci[8] = n1.w;

        float p[1 + NNEG];
#pragma unroll
        for (int c = 0; c < 1 + NNEG; ++c) {
            // ctx rows: 40% repeat-read -> leave cacheable (L2/LLC)
            const f32x4* crow = (const f32x4*)(ctx + (size_t)ci[c] * DIM);
            f32x4 c0 = crow[l16 * 2 + 0];
            f32x4 c1 = crow[l16 * 2 + 1];
            p[c] = e0.x * c0.x + e0.y * c0.y + e0.z * c0.z + e0.w * c0.w
                 + e1.x * c1.x + e1.y * c1.y + e1.z * c1.z + e1.w * c1.w;
        }

        // 4-stage butterfly within each 16-lane group; independent across c.
#pragma unroll
        for (int c = 0; c < 1 + NNEG; ++c) {
#pragma unroll
            for (int off = 8; off > 0; off >>= 1)
                p[c] += __shfl_xor(p[c], off, 16);
        }

        // sum softplus(-lg) + sum_n softplus(dn) = log((1+e^-lg)*prod(1+e^dn))
        float lg   = p[0];
        float prod = 1.0f + __expf(-lg);
        int rank = 1;
#pragma unroll
        for (int n = 1; n <= NNEG; ++n) {
            prod *= 1.0f + __expf(p[n]);
            rank += (p[n] >= lg) ? 1 : 0;     // ties favor negatives
        }
        loss_acc += __logf(prod);
        mrr_acc  += 1.0f / (float)rank;
    }

    // group lanes hold identical acc -> butterfly-sum the wave, scale by 1/16
    loss_acc *= 0.0625f;
    mrr_acc  *= 0.0625f;
#pragma unroll
    for (int off = 32; off > 0; off >>= 1) {
        loss_acc += __shfl_xor(loss_acc, off);
        mrr_acc  += __shfl_xor(mrr_acc,  off);
    }
    __shared__ float red[2 * 4];
    const int wib = threadIdx.x >> 6;
    if (lane == 0) {
        red[wib * 2 + 0] = loss_acc;
        red[wib * 2 + 1] = mrr_acc;
    }
    __syncthreads();
    if (threadIdx.x == 0) {
        float Ls = 0.0f, Ms = 0.0f;
#pragma unroll
        for (int w = 0; w < 4; ++w) { Ls += red[2 * w]; Ms += red[2 * w + 1]; }
        partials[blockIdx.x * 2 + 0] = Ls;
        partials[blockIdx.x * 2 + 1] = Ms;
    }
}

// 1-block reduction of per-block partials -> scalars {loss, mrr}
__global__ __launch_bounds__(256) void finalize(
    const float* __restrict__ partials,
    float*       __restrict__ scalars,
    int nblocks,
    float inv_n)
{
    float L = 0.0f, M = 0.0f;
    for (int i = threadIdx.x; i < nblocks; i += 256) {
        L += partials[2 * i + 0];
        M += partials[2 * i + 1];
    }
#pragma unroll
    for (int off = 32; off > 0; off >>= 1) {
        L += __shfl_xor(L, off);
        M += __shfl_xor(M, off);
    }
    __shared__ float red[2 * 4];
    const int wib = threadIdx.x >> 6;
    if ((threadIdx.x & 63) == 0) {
        red[wib * 2 + 0] = L;
        red[wib * 2 + 1] = M;
    }
    __syncthreads();
    if (threadIdx.x == 0) {
        float Ls = 0.0f, Ms = 0.0f;
#pragma unroll
        for (int w = 0; w < 4; ++w) { Ls += red[2 * w]; Ms += red[2 * w + 1]; }
        scalars[0] = Ls;
        scalars[1] = Ms * inv_n;
    }
}

extern "C" void kernel_launch(void* const* d_in, const int* in_sizes, int n_in,
                              void* d_out, int out_size, void* d_ws, size_t ws_size,
                              hipStream_t stream) {
    const int*   inputs = (const int*)d_in[0];
    const int*   src    = (const int*)d_in[1];
    const int*   pos    = (const int*)d_in[2];
    const int*   negs   = (const int*)d_in[3];
    const float* tgt    = (const float*)d_in[4];
    const float* ctx    = (const float*)d_in[5];

    const int b_in    = in_sizes[0];
    const int b_pairs = in_sizes[1];

    float* out      = (float*)d_out;
    float* out_emb  = out;
    float* out_ctx  = out + (size_t)b_in * DIM;
    float* scalars  = out + (size_t)2 * b_in * DIM;   // [loss, mrr]
    float* partials = (float*)d_ws;                    // [blocks * 2]

    // 2048 blocks x 256 = 8192 waves; grid-stride x4 in the pair phase.
    const int blocks = 2048;
    fused<<<blocks, 256, 0, stream>>>(inputs, src, pos, negs, tgt, ctx,
                                      out_emb, out_ctx, partials,
                                      b_in, b_pairs);
    finalize<<<1, 256, 0, stream>>>(partials, scalars, blocks,
                                    1.0f / (float)b_pairs);
}

// Round 8
// 141.104 us; speedup vs baseline: 1.7666x; 1.7666x over previous
//
#include <hip/hip_runtime.h>
#include <math.h>

// DeepWalk forward: embedding gathers + per-pair dot products -> loss & MRR.
// Round 8: clean revert to the round-4 variant (best measured: 126.2 us).
// Round 7's levers both backfired: __launch_bounds__(256,8) forced <=64 VGPR
// and spilled the pair loop (~80 live values) to scratch (126->249 us, ~2x);
// NT loads on src rows bypassed LLC that was absorbing ~40% of tgt reads.
// Structure: single fused kernel (gather phase + pair phase, 16 lanes/pair,
// grid-stride 2048 blocks), per-block partials in d_ws + finalize kernel,
// NT copies only in the gather phase (true single-use traffic).
// Evidence of the wall: rounds 2/4/5/6 = 133.9/126.2/129.4/134.1 us across
// four different structures; mandatory ~550MB unique + ~100-150MB L3-miss
// re-fetch @ ~5-5.5 TB/s random-gather BW -> floor ~110-125 us.

constexpr int DIM  = 128;
constexpr int NNEG = 8;

typedef float f32x4 __attribute__((ext_vector_type(4)));

__global__ __launch_bounds__(256) void fused(
    const int*   __restrict__ inputs,
    const int*   __restrict__ src,
    const int*   __restrict__ pos,
    const int*   __restrict__ negs,
    const float* __restrict__ tgt,
    const float* __restrict__ ctx,
    float*       __restrict__ out_emb,
    float*       __restrict__ out_ctx,
    float*       __restrict__ partials,   // [gridDim.x * 2]
    int b_in,
    int n_pairs)
{
    const int tid     = blockIdx.x * blockDim.x + threadIdx.x;
    const int nthread = gridDim.x * blockDim.x;

    // ---------------- phase 1: output gathers (copy, no reuse) -------------
    // one wave handles one input row for BOTH tables (lanes 0-31 tgt,
    // lanes 32-63 ctx); index load is wave-uniform; non-temporal to keep
    // L2/LLC for the pair phase's table rows.
    {
        const int total = b_in * 64;
        for (int u = tid; u < total; u += nthread) {
            int row   = u >> 6;
            int sub   = u & 63;
            int table = sub >> 5;
            int lane  = sub & 31;
            size_t idx = (size_t)inputs[row];
            const f32x4* s = (const f32x4*)((table ? ctx : tgt) + idx * DIM);
            f32x4 v = __builtin_nontemporal_load(s + lane);
            f32x4* d = (f32x4*)((table ? out_ctx : out_emb) + (size_t)row * DIM);
            __builtin_nontemporal_store(v, d + lane);
        }
    }

    // ---------------- phase 2: pair loss / mrr -----------------------------
    // 16 lanes per pair (lane holds 8 floats = 2 x float4), 4 pairs per wave.
    const int lane = threadIdx.x & 63;
    const int l16  = threadIdx.x & 15;
    const int gid  = tid >> 4;
    const int ngroups = nthread >> 4;

    float loss_acc = 0.0f;
    float mrr_acc  = 0.0f;

    for (int b = gid; b < n_pairs; b += ngroups) {
        int sidx = src[b];                                   // group-uniform
        const float4* srow = (const float4*)(tgt + (size_t)sidx * DIM);
        float4 e0 = srow[l16 * 2 + 0];
        float4 e1 = srow[l16 * 2 + 1];

        int ci[1 + NNEG];
        ci[0] = pos[b];
        const int4* np = (const int4*)(negs + (size_t)b * NNEG);
        int4 n0 = np[0];
        int4 n1 = np[1];
        ci[1] = n0.x; ci[2] = n0.y; ci[3] = n0.z; ci[4] = n0.w;
        ci[5] = n1.x; ci[6] = n1.y; ci[7] = n1.z; ci[8] = n1.w;

        float p[1 + NNEG];
#pragma unroll
        for (int c = 0; c < 1 + NNEG; ++c) {
            const float4* crow = (const float4*)(ctx + (size_t)ci[c] * DIM);
            float4 c0 = crow[l16 * 2 + 0];
            float4 c1 = crow[l16 * 2 + 1];
            p[c] = e0.x * c0.x + e0.y * c0.y + e0.z * c0.z + e0.w * c0.w
                 + e1.x * c1.x + e1.y * c1.y + e1.z * c1.z + e1.w * c1.w;
        }

        // 4-stage butterfly within each 16-lane group; independent across c.
#pragma unroll
        for (int c = 0; c < 1 + NNEG; ++c) {
#pragma unroll
            for (int off = 8; off > 0; off >>= 1)
                p[c] += __shfl_xor(p[c], off, 16);
        }

        // sum softplus(-lg) + sum_n softplus(dn) = log((1+e^-lg)*prod(1+e^dn))
        float lg   = p[0];
        float prod = 1.0f + __expf(-lg);
        int rank = 1;
#pragma unroll
        for (int n = 1; n <= NNEG; ++n) {
            prod *= 1.0f + __expf(p[n]);
            rank += (p[n] >= lg) ? 1 : 0;     // ties favor negatives
        }
        loss_acc += __logf(prod);
        mrr_acc  += 1.0f / (float)rank;
    }

    // group lanes hold identical acc -> keep l16==0 lanes, butterfly the wave
    float L = (l16 == 0) ? loss_acc : 0.0f;
    float M = (l16 == 0) ? mrr_acc  : 0.0f;
#pragma unroll
    for (int off = 32; off > 0; off >>= 1) {
        L += __shfl_xor(L, off);
        M += __shfl_xor(M, off);
    }
    __shared__ float red[2 * 4];
    const int wib = threadIdx.x >> 6;
    if (lane == 0) {
        red[wib * 2 + 0] = L;
        red[wib * 2 + 1] = M;
    }
    __syncthreads();
    if (threadIdx.x == 0) {
        float Ls = 0.0f, Ms = 0.0f;
#pragma unroll
        for (int w = 0; w < 4; ++w) { Ls += red[2 * w]; Ms += red[2 * w + 1]; }
        partials[blockIdx.x * 2 + 0] = Ls;
        partials[blockIdx.x * 2 + 1] = Ms;
    }
}

// 1-block reduction of per-block partials -> scalars {loss, mrr}
__global__ __launch_bounds__(256) void finalize(
    const float* __restrict__ partials,
    float*       __restrict__ scalars,
    int nblocks,
    float inv_n)
{
    float L = 0.0f, M = 0.0f;
    for (int i = threadIdx.x; i < nblocks; i += 256) {
        L += partials[2 * i + 0];
        M += partials[2 * i + 1];
    }
#pragma unroll
    for (int off = 32; off > 0; off >>= 1) {
        L += __shfl_xor(L, off);
        M += __shfl_xor(M, off);
    }
    __shared__ float red[2 * 4];
    const int wib = threadIdx.x >> 6;
    if ((threadIdx.x & 63) == 0) {
        red[wib * 2 + 0] = L;
        red[wib * 2 + 1] = M;
    }
    __syncthreads();
    if (threadIdx.x == 0) {
        float Ls = 0.0f, Ms = 0.0f;
#pragma unroll
        for (int w = 0; w < 4; ++w) { Ls += red[2 * w]; Ms += red[2 * w + 1]; }
        scalars[0] = Ls;
        scalars[1] = Ms * inv_n;
    }
}

extern "C" void kernel_launch(void* const* d_in, const int* in_sizes, int n_in,
                              void* d_out, int out_size, void* d_ws, size_t ws_size,
                              hipStream_t stream) {
    const int*   inputs = (const int*)d_in[0];
    const int*   src    = (const int*)d_in[1];
    const int*   pos    = (const int*)d_in[2];
    const int*   negs   = (const int*)d_in[3];
    const float* tgt    = (const float*)d_in[4];
    const float* ctx    = (const float*)d_in[5];

    const int b_in    = in_sizes[0];
    const int b_pairs = in_sizes[1];

    float* out      = (float*)d_out;
    float* out_emb  = out;
    float* out_ctx  = out + (size_t)b_in * DIM;
    float* scalars  = out + (size_t)2 * b_in * DIM;   // [loss, mrr]
    float* partials = (float*)d_ws;                    // [blocks * 2]

    // 2048 blocks x 256 = 8192 waves = exactly 32 waves/CU on 256 CUs.
    const int blocks = 2048;
    fused<<<blocks, 256, 0, stream>>>(inputs, src, pos, negs, tgt, ctx,
                                      out_emb, out_ctx, partials,
                                      b_in, b_pairs);
    finalize<<<1, 256, 0, stream>>>(partials, scalars, blocks,
                                    1.0f / (float)b_pairs);
}